// Round 13
// baseline (69.319 us; speedup 1.0000x reference)
//
#include <hip/hip_runtime.h>
#include <math.h>

typedef unsigned short u16;
typedef unsigned int   u32;

using bf16x8 = __attribute__((ext_vector_type(8))) short;
using f32x4  = __attribute__((ext_vector_type(4))) float;

#define NB   64
#define NE   8
#define DIN  320
#define NP   196
#define CK   768
#define CN   768
#define ESTR (768 * 768)
#define NKT  24      // K-steps of 32

#define GATE_BLOCKS  8
#define WCONV_BLOCKS 1152   // 8*768*768 / (16*256)
#define PATCH_BLOCKS 2352   // 64*196*48 / 256

__device__ __forceinline__ u16 f2bf(float f) {
    u32 u = __builtin_bit_cast(u32, f);
    u += 0x7fffu + ((u >> 16) & 1u);
    return (u16)(u >> 16);
}

__device__ __forceinline__ void gload16(const void* g, void* l) {
    __builtin_amdgcn_global_load_lds(
        (const __attribute__((address_space(1))) void*)g,
        (__attribute__((address_space(3))) void*)l, 16, 0, 0);
}

// ---------------- prep1: gate1 + wconv + row-major patchify (R10-verified) ----------------
__global__ __launch_bounds__(256) void prep1_kernel(
    const float* __restrict__ x,
    const float* __restrict__ g,
    const float* __restrict__ noise,
    const float* __restrict__ w_gate,
    const float* __restrict__ w_noise,
    const float* __restrict__ w_exp,
    float* __restrict__ gCl, float* __restrict__ gSd, float* __restrict__ gNy,
    u16* __restrict__ patches,
    u16* __restrict__ wb)
{
    __shared__ float sW[DIN][NE + 1];
    __shared__ float sWn[DIN][NE + 1];
    const int t = threadIdx.x;
    int bid = blockIdx.x;

    if (bid < GATE_BLOCKS) {
        for (int i = t; i < DIN * NE; i += 256) {
            sW[i >> 3][i & 7]  = w_gate[i];
            sWn[i >> 3][i & 7] = w_noise[i];
        }
        __syncthreads();
        const int pair = t >> 2, q = t & 3;
        const int bl = pair >> 3, e = pair & 7;
        const int b = bid * 8 + bl;
        float cl = 0.f, nz = 0.f;
        const float* gr = g + b * DIN + q * 80;
        #pragma unroll 4
        for (int j = 0; j < 80; ++j) {
            float gv = gr[j];
            cl = fmaf(gv, sW[q * 80 + j][e], cl);
            nz = fmaf(gv, sWn[q * 80 + j][e], nz);
        }
        cl += __shfl_xor(cl, 1); cl += __shfl_xor(cl, 2);
        nz += __shfl_xor(nz, 1); nz += __shfl_xor(nz, 2);
        if (q == 0) {
            int p = b * NE + e;
            // jax.nn.softplus == max(x,0)+log1p(exp(-|x|))
            float sd = fmaxf(nz, 0.f) + log1pf(expf(-fabsf(nz))) + 0.01f;
            gCl[p] = cl; gSd[p] = sd;
            gNy[p] = fmaf(noise[p], sd, cl);
        }
        return;
    }
    bid -= GATE_BLOCKS;

    if (bid < WCONV_BLOCKS) {
        int idx = bid * 256 + t;
        const float* src = w_exp + (size_t)idx * 16;
        u16* dst = wb + (size_t)idx * 16;
        float4 f0 = *reinterpret_cast<const float4*>(src);
        float4 f1 = *reinterpret_cast<const float4*>(src + 4);
        float4 f2 = *reinterpret_cast<const float4*>(src + 8);
        float4 f3 = *reinterpret_cast<const float4*>(src + 12);
        uint4 o0, o1;
        o0.x = (u32)f2bf(f0.x) | ((u32)f2bf(f0.y) << 16);
        o0.y = (u32)f2bf(f0.z) | ((u32)f2bf(f0.w) << 16);
        o0.z = (u32)f2bf(f1.x) | ((u32)f2bf(f1.y) << 16);
        o0.w = (u32)f2bf(f1.z) | ((u32)f2bf(f1.w) << 16);
        o1.x = (u32)f2bf(f2.x) | ((u32)f2bf(f2.y) << 16);
        o1.y = (u32)f2bf(f2.z) | ((u32)f2bf(f2.w) << 16);
        o1.z = (u32)f2bf(f3.x) | ((u32)f2bf(f3.y) << 16);
        o1.w = (u32)f2bf(f3.z) | ((u32)f2bf(f3.w) << 16);
        *reinterpret_cast<uint4*>(dst)     = o0;
        *reinterpret_cast<uint4*>(dst + 8) = o1;
        return;
    }
    bid -= WCONV_BLOCKS;

    // patchify -> bf16 row-major [b][256-stride][768], rows < 196 only
    int idx = bid * 256 + t;
    int ph = idx & 15;
    int c  = (idx >> 4) % 3;
    int p  = (idx / 48) % NP;
    int b  = idx / (48 * NP);
    const float* src = x + (((size_t)(b * 3 + c) * 224 + (p / 14) * 16 + ph) * 224
                            + (p % 14) * 16);
    u16* dst = patches + ((size_t)b * 256 + p) * CK + c * 256 + ph * 16;
    float4 f0 = *reinterpret_cast<const float4*>(src);
    float4 f1 = *reinterpret_cast<const float4*>(src + 4);
    float4 f2 = *reinterpret_cast<const float4*>(src + 8);
    float4 f3 = *reinterpret_cast<const float4*>(src + 12);
    uint4 o0, o1;
    o0.x = (u32)f2bf(f0.x) | ((u32)f2bf(f0.y) << 16);
    o0.y = (u32)f2bf(f0.z) | ((u32)f2bf(f0.w) << 16);
    o0.z = (u32)f2bf(f1.x) | ((u32)f2bf(f1.y) << 16);
    o0.w = (u32)f2bf(f1.z) | ((u32)f2bf(f1.w) << 16);
    o1.x = (u32)f2bf(f2.x) | ((u32)f2bf(f2.y) << 16);
    o1.y = (u32)f2bf(f2.z) | ((u32)f2bf(f2.w) << 16);
    o1.z = (u32)f2bf(f3.x) | ((u32)f2bf(f3.y) << 16);
    o1.w = (u32)f2bf(f3.z) | ((u32)f2bf(f3.w) << 16);
    *reinterpret_cast<uint4*>(dst)     = o0;
    *reinterpret_cast<uint4*>(dst + 8) = o1;
}

// ---------------- gate2: top-2, probs, loss, eid, expert-sorted perm ----------------
__global__ __launch_bounds__(512) void gate2_kernel(
    const float* __restrict__ gCl,
    const float* __restrict__ gSd,
    const float* __restrict__ gNy,
    int* __restrict__ eid,
    int* __restrict__ perm,
    float* __restrict__ loss_out)
{
    __shared__ float sNy[NB][NE];
    __shared__ float sProb[NB][NE];
    __shared__ int   sTop[NB];
    __shared__ float sImp[NE], sLoad[NE];
    const int t = threadIdx.x;
    const int b = t >> 3, e = t & 7;
    float cl = gCl[t], sd = gSd[t], ny = gNy[t];
    sNy[b][e] = ny;
    __syncthreads();
    float v1 = -1e30f, v2 = -1e30f; int i1 = 0;
    #pragma unroll
    for (int k2 = 0; k2 < NE; ++k2) {
        float v = sNy[b][k2];
        if (v > v1) { v2 = v1; v1 = v; i1 = k2; }
        else if (v > v2) { v2 = v; }
    }
    if (e == 0) { sTop[b] = i1; eid[b] = i1; }
    // is_in: noisy > 2nd-largest (thr_in=v2); else threshold = largest (v1)
    float thr = (ny > v2) ? v2 : v1;
    float z = (cl - thr) / sd;
    sProb[b][e] = 0.5f * (1.0f + erff(z * 0.7071067811865476f));
    __syncthreads();
    if (t < NE) {
        float imp = 0.f, ld = 0.f;
        for (int i = 0; i < NB; ++i) {
            imp += (sTop[i] == t) ? 1.0f : 0.0f;
            ld  += sProb[i][t];
        }
        sImp[t] = imp; sLoad[t] = ld;
    }
    __syncthreads();
    if (t == 0) {
        float mi = 0.f, ml = 0.f;
        for (int k2 = 0; k2 < NE; ++k2) { mi += sImp[k2]; ml += sLoad[k2]; }
        mi *= (1.0f / NE); ml *= (1.0f / NE);
        float vi = 0.f, vl = 0.f;
        for (int k2 = 0; k2 < NE; ++k2) {
            float d1 = sImp[k2] - mi;  vi += d1 * d1;
            float d2 = sLoad[k2] - ml; vl += d2 * d2;
        }
        vi *= (1.0f / (NE - 1)); vl *= (1.0f / (NE - 1));  // ddof=1
        loss_out[0] = (vi / (mi * mi + 1e-10f) + vl / (ml * ml + 1e-10f)) * 0.01f;
        // expert-sorted stable permutation of images (L2 locality for B)
        int off[NE]; int s = 0;
        #pragma unroll
        for (int k2 = 0; k2 < NE; ++k2) { off[k2] = s; s += (int)sImp[k2]; }
        for (int i = 0; i < NB; ++i) perm[off[sTop[i]]++] = i;
    }
}

// ---------------- expert GEMM: 128x64 tiles, 2-phase LDS dbuf, 5-6 blocks/CU ----------------
// 1536 blocks = (image via perm, mt 0/1, nt 0..11); 256 thr = 4 waves, wave =
// 32 rows x 64 cols (2x4 frags, 8 MFMA/step). LDS per buffer: A 8KB | B 4KB,
// double-buffered (24KB) -> 5+ independent barrier domains per CU so one
// block's vmcnt/barrier stall overlaps other blocks' MFMA issue (the R5
// structure's measured dead time). R5-proven both-sides chunk swizzle
// cg = (l&3)^(l>>4), read chunk c = (l>>4)^((row>>2)&3).
__global__ __launch_bounds__(256, 5) void gemm_kernel(
    const u16* __restrict__ patches,
    const u16* __restrict__ wbf,
    const float* __restrict__ b_exp,
    const int* __restrict__ eid,
    const int* __restrict__ perm,
    float* __restrict__ out)
{
    __shared__ char smem[2][12288];   // A 8KB | B 4KB per buffer

    const int id = blockIdx.x;
    // bijective XCD swizzle: 192 consecutive virtual blocks (=8 sorted images) per XCD
    const int v  = (id & 7) * 192 + (id >> 3);
    const int b  = perm[v / 24];
    const int rr = v % 24;
    const int mt = rr / 12;
    const int n0 = (rr % 12) * 64;
    const int e  = eid[b];

    const int t  = threadIdx.x;
    const int l  = t & 63;
    const int w  = t >> 6;        // wave = m-slice of 32 rows

    // ---- staging ----
    // A: 512 chunks (128 rows x 4); thread t handles chunks {t, t+256}
    //    chunk q -> row q>>2, LDS byte q*16; source chunk cg = (l&3)^(l>>4)
    // B: 256 chunks (64 rows x 4); thread t handles chunk t at Boff + t*16
    const u32 cg = (u32)((l & 3) ^ (l >> 4));
    const u16* aS0 = patches + ((size_t)b * 256 + mt * 128 + (w << 4) + (l >> 2)) * CK + cg * 8;
    const u16* aS1 = aS0 + (size_t)64 * CK;
    const u16* bS  = wbf + (size_t)e * ESTR + ((size_t)n0 + (w << 4) + (l >> 2)) * CK + cg * 8;
    const u32 dA0 = ((u32)w << 10) + ((u32)l << 4);          // w*1024 + l*16
    const u32 dA1 = dA0 + 4096;
    const u32 dB  = 8192u + dA0;

    // ---- read offsets ----
    u32 aOff[2], bOff[4];
    #pragma unroll
    for (int fm = 0; fm < 2; ++fm) {
        int row = w * 32 + fm * 16 + (l & 15);
        aOff[fm] = (u32)(row * 64) + (((u32)(l >> 4) ^ (u32)((row >> 2) & 3)) << 4);
    }
    #pragma unroll
    for (int fn = 0; fn < 4; ++fn) {
        int row = fn * 16 + (l & 15);
        bOff[fn] = 8192u + (u32)(row * 64) + (((u32)(l >> 4) ^ (u32)((row >> 2) & 3)) << 4);
    }

    f32x4 acc[2][4];
    #pragma unroll
    for (int fm = 0; fm < 2; ++fm)
        #pragma unroll
        for (int fn = 0; fn < 4; ++fn)
            acc[fm][fn] = (f32x4){0.f, 0.f, 0.f, 0.f};

    char* sm = &smem[0][0];

    // prologue: stage tile 0 -> buf 0
    gload16(aS0, sm + dA0);
    gload16(aS1, sm + dA1);
    gload16(bS,  sm + dB);

    for (int kt = 0; kt < NKT - 1; ++kt) {
        // prefetch tile kt+1 into other buffer
        char* sn = sm + (u32)(((kt + 1) & 1) * 12288);
        gload16(aS0 + (kt + 1) * 32, sn + dA0);
        gload16(aS1 + (kt + 1) * 32, sn + dA1);
        gload16(bS  + (kt + 1) * 32, sn + dB);

        // wait only tile kt's 3 loads; prefetch's 3 stay in flight
        asm volatile("s_waitcnt vmcnt(3)" ::: "memory");
        __builtin_amdgcn_s_barrier();

        char* sc = sm + (u32)((kt & 1) * 12288);
        bf16x8 af[2], bfr[4];
        #pragma unroll
        for (int fm = 0; fm < 2; ++fm)
            af[fm] = *reinterpret_cast<const bf16x8*>(sc + aOff[fm]);
        #pragma unroll
        for (int fn = 0; fn < 4; ++fn)
            bfr[fn] = *reinterpret_cast<const bf16x8*>(sc + bOff[fn]);

        __builtin_amdgcn_s_setprio(1);
        #pragma unroll
        for (int fm = 0; fm < 2; ++fm)
            #pragma unroll
            for (int fn = 0; fn < 4; ++fn)
                acc[fm][fn] = __builtin_amdgcn_mfma_f32_16x16x32_bf16(
                    af[fm], bfr[fn], acc[fm][fn], 0, 0, 0);
        __builtin_amdgcn_s_setprio(0);

        __builtin_amdgcn_s_barrier();   // reads done before buffer reuse
    }

    // epilogue tile NKT-1
    asm volatile("s_waitcnt vmcnt(0)" ::: "memory");
    __builtin_amdgcn_s_barrier();
    {
        char* sc = sm + (u32)(((NKT - 1) & 1) * 12288);
        bf16x8 af[2], bfr[4];
        #pragma unroll
        for (int fm = 0; fm < 2; ++fm)
            af[fm] = *reinterpret_cast<const bf16x8*>(sc + aOff[fm]);
        #pragma unroll
        for (int fn = 0; fn < 4; ++fn)
            bfr[fn] = *reinterpret_cast<const bf16x8*>(sc + bOff[fn]);
        #pragma unroll
        for (int fm = 0; fm < 2; ++fm)
            #pragma unroll
            for (int fn = 0; fn < 4; ++fn)
                acc[fm][fn] = __builtin_amdgcn_mfma_f32_16x16x32_bf16(
                    af[fm], bfr[fn], acc[fm][fn], 0, 0, 0);
    }

    // ---- store: bias + eps-replace, rows < 196 only ----
    const int r4 = (l >> 4) * 4;
    #pragma unroll
    for (int fm = 0; fm < 2; ++fm) {
        int mb = mt * 128 + w * 32 + fm * 16 + r4;
        #pragma unroll
        for (int fn = 0; fn < 4; ++fn) {
            int col = n0 + fn * 16 + (l & 15);
            float bias = b_exp[e * CN + col];
            #pragma unroll
            for (int q = 0; q < 4; ++q) {
                int mrow = mb + q;
                if (mrow < NP) {
                    float vv = acc[fm][fn][q] + bias;
                    if (vv == 0.0f) vv = 2.220446049250313e-16f;
                    out[((size_t)b * NP + mrow) * CN + col] = vv;
                }
            }
        }
    }
}

extern "C" void kernel_launch(void* const* d_in, const int* in_sizes, int n_in,
                              void* d_out, int out_size, void* d_ws, size_t ws_size,
                              hipStream_t stream) {
    const float* x       = (const float*)d_in[0];
    const float* g       = (const float*)d_in[1];
    const float* noise   = (const float*)d_in[2];
    const float* w_gate  = (const float*)d_in[3];
    const float* w_noise = (const float*)d_in[4];
    const float* w_exp   = (const float*)d_in[5];
    const float* b_exp   = (const float*)d_in[6];
    float* out = (float*)d_out;

    char* ws = (char*)d_ws;
    int*   eid     = (int*)ws;                    // 256 B
    int*   perm    = (int*)(ws + 256);            // 256 B
    float* gCl     = (float*)(ws + 512);
    float* gSd     = (float*)(ws + 2560);
    float* gNy     = (float*)(ws + 4608);
    u16*   patches = (u16*)(ws + 8192);                             // 64*256*768*2
    u16*   wbf     = (u16*)(ws + 8192 + (size_t)NB * 256 * CK * 2); // 8*768*768*2

    hipLaunchKernelGGL(prep1_kernel,
                       dim3(GATE_BLOCKS + WCONV_BLOCKS + PATCH_BLOCKS), dim3(256), 0, stream,
                       x, g, noise, w_gate, w_noise, w_exp, gCl, gSd, gNy, patches, wbf);
    hipLaunchKernelGGL(gate2_kernel, dim3(1), dim3(512), 0, stream,
                       gCl, gSd, gNy, eid, perm, out + (size_t)NB * NP * CN);
    hipLaunchKernelGGL(gemm_kernel, dim3(1536), dim3(256), 0, stream,
                       patches, wbf, b_exp, eid, perm, out);
}